// Round 3
// baseline (365.803 us; speedup 1.0000x reference)
//
#include <hip/hip_runtime.h>

// 2-layer tanh RNN, fused, f32, fully wave-synchronous, NO barriers in loop.
// B=4096 chains, T=512 steps, H=20.
// Block = 1 wave (64 lanes) = GB=3 batches (lanes 0..59; 60..63 benign dups).
// h-state lives in REGISTERS (thread (g,j) owns h0[g][j], h1[g][j]);
// broadcast via ds_bpermute (register crossbar) -- no LDS round trip, no
// __syncthreads, no vmcnt drain. x pre-staged to LDS (zero global ops in
// the recurrence loop). Layer1 pipelined one step behind layer0.

#define Bsz 4096
#define Tn  512
#define Hn  20
#define GB  3
#define NTHREADS 64

__device__ __forceinline__ float tanh_fast(float v) {
    // tanh(v) = 1 - 2/(exp(2v)+1); v_exp_f32 + v_rcp_f32.
    float e = __expf(2.0f * v);
    return 1.0f - 2.0f * __builtin_amdgcn_rcpf(e + 1.0f);
}

__device__ __forceinline__ float bperm(int byteaddr, float v) {
    return __int_as_float(__builtin_amdgcn_ds_bpermute(byteaddr, __float_as_int(v)));
}

__global__ __launch_bounds__(NTHREADS)
void rnn2_fused(const float* __restrict__ x,        // [B,T,1]
                const float* __restrict__ hidden,   // [2,B,H]
                const float* __restrict__ W_ih0,    // [H,1]
                const float* __restrict__ W_hh0,    // [H,H]
                const float* __restrict__ b_ih0,    // [H]
                const float* __restrict__ b_hh0,    // [H]
                const float* __restrict__ W_ih1,    // [H,H]
                const float* __restrict__ W_hh1,    // [H,H]
                const float* __restrict__ b_ih1,    // [H]
                const float* __restrict__ b_hh1,    // [H]
                const float* __restrict__ fc_w,     // [1,H]
                const float* __restrict__ fc_b,     // [1]
                float* __restrict__ out)            // [B] ++ [2,B,H] flat
{
    const int tid = threadIdx.x;
    int g = tid / Hn;                  // 0..3
    int j = tid - g * Hn;              // 0..19 (0..3 for tid>=60)
    const bool lane_ok = (tid < GB * Hn);
    if (!lane_ok) g = GB - 1;          // lanes 60..63 duplicate batch 2

    const int  b        = blockIdx.x * GB + g;
    const bool b_ok     = (b < Bsz);
    const int  bl       = b_ok ? b : (Bsz - 1);
    const bool store_ok = lane_ok && b_ok;

    __shared__ float xs[GB * Tn];      // 6 KB: all x for this block

    // stage x (coalesced float4; OOB chunks -> 0, results discarded anyway)
    {
        const long gbase = (long)blockIdx.x * (GB * Tn);
        #pragma unroll
        for (int r = 0; r < (GB * Tn) / (NTHREADS * 4); ++r) {  // 6 rounds
            const int c = (r * NTHREADS + tid) * 4;
            float4 v = make_float4(0.f, 0.f, 0.f, 0.f);
            if (gbase + c + 3 < (long)Bsz * Tn)
                v = *(const float4*)(x + gbase + c);
            *(float4*)&xs[c] = v;
        }
    }

    // per-thread weight rows (80B rows => 16B-aligned float4 loads)
    float whh0[Hn], wih1[Hn], whh1[Hn];
    {
        const float4* p0 = (const float4*)(W_hh0 + j * Hn);
        const float4* p1 = (const float4*)(W_ih1 + j * Hn);
        const float4* p2 = (const float4*)(W_hh1 + j * Hn);
        #pragma unroll
        for (int r = 0; r < 5; ++r) {
            *(float4*)&whh0[4*r] = p0[r];
            *(float4*)&wih1[4*r] = p1[r];
            *(float4*)&whh1[4*r] = p2[r];
        }
    }
    const float wih0  = W_ih0[j];
    const float bias0 = b_ih0[j] + b_hh0[j];
    const float bias1 = b_ih1[j] + b_hh1[j];

    // bpermute byte-addresses: element k of my batch lives in lane g*20+k
    int addr[Hn];
    #pragma unroll
    for (int k = 0; k < Hn; ++k) addr[k] = (g * Hn + k) * 4;

    // register-resident state
    float h0o = hidden[bl * Hn + j];
    float h1o = hidden[(long)Bsz * Hn + bl * Hn + j];

    __syncthreads();                   // xs visible (once; single wave, cheap)

    float xt = xs[g * Tn];

    // iter i: layer0 computes h0[i] (i<T), layer1 computes h1[i-1] (i>0).
    // gathers read h0o==h0[i-1], h1o==h1[i-2]; updates applied at iter end.
    #pragma unroll 4
    for (int i = 0; i <= Tn; ++i) {
        float h0p[Hn], h1p[Hn];
        #pragma unroll
        for (int k = 0; k < Hn; ++k) h0p[k] = bperm(addr[k], h0o);
        #pragma unroll
        for (int k = 0; k < Hn; ++k) h1p[k] = bperm(addr[k], h1o);

        // next x from LDS (used next iteration -> latency hidden)
        const int tn = (i + 1 < Tn) ? (i + 1) : (Tn - 1);
        const float xn = xs[g * Tn + tn];

        // even/odd accumulator split (pairs 2k,2k+1 -> v_pk_fma_f32-able)
        float a0x = fmaf(xt, wih0, bias0), a0y = 0.f;
        float a1x = bias1,                 a1y = 0.f;
        float a2x = 0.f,                   a2y = 0.f;
        #pragma unroll
        for (int k = 0; k < 10; ++k) {
            a0x = fmaf(whh0[2*k],   h0p[2*k],   a0x);
            a0y = fmaf(whh0[2*k+1], h0p[2*k+1], a0y);
            a1x = fmaf(wih1[2*k],   h0p[2*k],   a1x);
            a1y = fmaf(wih1[2*k+1], h0p[2*k+1], a1y);
            a2x = fmaf(whh1[2*k],   h1p[2*k],   a2x);
            a2y = fmaf(whh1[2*k+1], h1p[2*k+1], a2y);
        }

        const float n0 = tanh_fast(a0x + a0y);
        const float n1 = tanh_fast((a1x + a1y) + (a2x + a2y));

        if (i < Tn) h0o = n0;          // uniform predicate -> select, cheap
        if (i > 0)  h1o = n1;
        xt = xn;
    }

    // epilogue: h0o = h0[511], h1o = h1[511]
    float h1f[Hn];
    #pragma unroll
    for (int k = 0; k < Hn; ++k) h1f[k] = bperm(addr[k], h1o);

    if (store_ok) {
        out[Bsz + b * Hn + j]                  = h0o;   // new_hidden[0]
        out[Bsz + (long)Bsz * Hn + b * Hn + j] = h1o;   // new_hidden[1]
        if (j == 0) {                                    // fc head
            float acc = fc_b[0];
            #pragma unroll
            for (int k = 0; k < Hn; ++k)
                acc = fmaf(fc_w[k], h1f[k], acc);
            out[b] = acc;
        }
    }
}

extern "C" void kernel_launch(void* const* d_in, const int* in_sizes, int n_in,
                              void* d_out, int out_size, void* d_ws, size_t ws_size,
                              hipStream_t stream) {
    const float* x      = (const float*)d_in[0];
    const float* hidden = (const float*)d_in[1];
    const float* W_ih0  = (const float*)d_in[2];
    const float* W_hh0  = (const float*)d_in[3];
    const float* b_ih0  = (const float*)d_in[4];
    const float* b_hh0  = (const float*)d_in[5];
    const float* W_ih1  = (const float*)d_in[6];
    const float* W_hh1  = (const float*)d_in[7];
    const float* b_ih1  = (const float*)d_in[8];
    const float* b_hh1  = (const float*)d_in[9];
    const float* fc_w   = (const float*)d_in[10];
    const float* fc_b   = (const float*)d_in[11];

    const int nblocks = (Bsz + GB - 1) / GB;   // 1366
    rnn2_fused<<<nblocks, NTHREADS, 0, stream>>>(
        x, hidden, W_ih0, W_hh0, b_ih0, b_hh0,
        W_ih1, W_hh1, b_ih1, b_hh1, fc_w, fc_b, (float*)d_out);
}

// Round 4
// 175.035 us; speedup vs baseline: 2.0899x; 2.0899x over previous
//
#include <hip/hip_runtime.h>

// 2-layer tanh RNN, fused, f32, single-wave blocks, zero global ops in loop.
// B=4096 chains, T=512 steps, H=20.
// Block = 1 wave = GB=3 batches (lanes 0..59 active; 60..63 benign dups).
// h-state in LDS double buffer, gathered via broadcast ds_read_b128
// (conflict-free, R1/R2-verified). ALL x pre-staged to LDS so the per-iter
// __syncthreads() drains only lgkmcnt (no global-load latency on the
// critical path -- R2's hidden cost). Layer1 pipelined one step behind.

#define Bsz 4096
#define Tn  512
#define Hn  20
#define GB  3
#define NTHREADS 64

__device__ __forceinline__ float tanh_fast(float v) {
    // tanh(v) = 1 - 2/(exp(2v)+1); v_exp_f32 + v_rcp_f32.
    float e = __expf(2.0f * v);
    return 1.0f - 2.0f * __builtin_amdgcn_rcpf(e + 1.0f);
}

__global__ __launch_bounds__(NTHREADS)
void rnn2_fused(const float* __restrict__ x,        // [B,T,1]
                const float* __restrict__ hidden,   // [2,B,H]
                const float* __restrict__ W_ih0,    // [H,1]
                const float* __restrict__ W_hh0,    // [H,H]
                const float* __restrict__ b_ih0,    // [H]
                const float* __restrict__ b_hh0,    // [H]
                const float* __restrict__ W_ih1,    // [H,H]
                const float* __restrict__ W_hh1,    // [H,H]
                const float* __restrict__ b_ih1,    // [H]
                const float* __restrict__ b_hh1,    // [H]
                const float* __restrict__ fc_w,     // [1,H]
                const float* __restrict__ fc_b,     // [1]
                float* __restrict__ out)            // [B] ++ [2,B,H] flat
{
    const int tid = threadIdx.x;
    int g = tid / Hn;                  // 0..3
    int j = tid - g * Hn;              // 0..19 (0..3 for tid>=60)
    const bool lane_ok = (tid < GB * Hn);
    if (!lane_ok) g = GB - 1;          // lanes 60..63 duplicate batch 2

    const int  b        = blockIdx.x * GB + g;
    const bool b_ok     = (b < Bsz);
    const int  bl       = b_ok ? b : (Bsz - 1);
    const bool store_ok = lane_ok && b_ok;

    __shared__ float xs[GB * Tn];      // 6 KB: all x for this block's batches
    __shared__ float h0s[2][GB][Hn];   // double-buffered hidden state
    __shared__ float h1s[2][GB][Hn];

    // stage ALL x up front (coalesced float4; OOB -> 0, results discarded)
    {
        const long gbase = (long)blockIdx.x * (GB * Tn);
        #pragma unroll
        for (int r = 0; r < (GB * Tn) / (NTHREADS * 4); ++r) {  // 6 rounds
            const int c = (r * NTHREADS + tid) * 4;
            float4 v = make_float4(0.f, 0.f, 0.f, 0.f);
            if (gbase + c + 3 < (long)Bsz * Tn)
                v = *(const float4*)(x + gbase + c);
            *(float4*)&xs[c] = v;
        }
    }

    // per-thread weight rows (80B rows => 16B-aligned float4 loads)
    float whh0[Hn], wih1[Hn], whh1[Hn];
    {
        const float4* p0 = (const float4*)(W_hh0 + j * Hn);
        const float4* p1 = (const float4*)(W_ih1 + j * Hn);
        const float4* p2 = (const float4*)(W_hh1 + j * Hn);
        #pragma unroll
        for (int r = 0; r < 5; ++r) {
            *(float4*)&whh0[4*r] = p0[r];
            *(float4*)&wih1[4*r] = p1[r];
            *(float4*)&whh1[4*r] = p2[r];
        }
    }
    const float wih0  = W_ih0[j];
    const float bias0 = b_ih0[j] + b_hh0[j];
    const float bias1 = b_ih1[j] + b_hh1[j];

    // init: h0 -> buf0; h1 -> buf0 AND buf1 (layer1's first read is from
    // buf1 at i=1, which i=0 does not write)
    h0s[0][g][j] = hidden[bl * Hn + j];
    const float h1i = hidden[(long)Bsz * Hn + bl * Hn + j];
    h1s[0][g][j] = h1i;
    h1s[1][g][j] = h1i;

    __syncthreads();                   // xs + init visible; x loads done here
    float xt = xs[g * Tn];

    // iter i: layer0 computes h0[i] (i<T), layer1 computes h1[i-1] (i>0).
    // reads buf p=i&1 (h0[i-1], h1[i-2]); writes buf p^1.
    // NO global memory ops inside -> barrier drains only lgkmcnt.
    #pragma unroll 2
    for (int i = 0; i <= Tn; ++i) {
        const int p = i & 1, q = p ^ 1;

        float h0p[Hn], h1p[Hn];
        #pragma unroll
        for (int r = 0; r < 5; ++r) {
            *(float4*)&h0p[4*r] = *(const float4*)&h0s[p][g][4*r];
            *(float4*)&h1p[4*r] = *(const float4*)&h1s[p][g][4*r];
        }

        // next x from LDS (broadcast within group; off critical path)
        const int tn = (i + 1 < Tn) ? (i + 1) : (Tn - 1);
        const float xn = xs[g * Tn + tn];

        // even/odd accumulator split (enables v_pk_fma_f32 packing)
        float a0x = fmaf(xt, wih0, bias0), a0y = 0.f;
        float a1x = bias1,                 a1y = 0.f;
        float a2x = 0.f,                   a2y = 0.f;
        #pragma unroll
        for (int k = 0; k < 10; ++k) {
            a0x = fmaf(whh0[2*k],   h0p[2*k],   a0x);
            a0y = fmaf(whh0[2*k+1], h0p[2*k+1], a0y);
            a1x = fmaf(wih1[2*k],   h0p[2*k],   a1x);
            a1y = fmaf(wih1[2*k+1], h0p[2*k+1], a1y);
            a2x = fmaf(whh1[2*k],   h1p[2*k],   a2x);
            a2y = fmaf(whh1[2*k+1], h1p[2*k+1], a2y);
        }

        const float n0 = tanh_fast(a0x + a0y);
        const float n1 = tanh_fast((a1x + a1y) + (a2x + a2y));

        if (i < Tn) h0s[q][g][j] = n0;
        if (i > 0)  h1s[q][g][j] = n1;

        xt = xn;
        __syncthreads();   // lgkm-only drain (single wave, no globals)
    }

    // final states: h0[511] written at i=511 -> buf0; h1[511] at i=512 -> buf1
    if (store_ok) {
        out[Bsz + b * Hn + j]                  = h0s[0][g][j];   // new_hidden[0]
        out[Bsz + (long)Bsz * Hn + b * Hn + j] = h1s[1][g][j];   // new_hidden[1]
        if (j == 0) {                                             // fc head
            float acc = fc_b[0];
            #pragma unroll
            for (int k = 0; k < Hn; ++k)
                acc = fmaf(fc_w[k], h1s[1][g][k], acc);
            out[b] = acc;
        }
    }
}

extern "C" void kernel_launch(void* const* d_in, const int* in_sizes, int n_in,
                              void* d_out, int out_size, void* d_ws, size_t ws_size,
                              hipStream_t stream) {
    const float* x      = (const float*)d_in[0];
    const float* hidden = (const float*)d_in[1];
    const float* W_ih0  = (const float*)d_in[2];
    const float* W_hh0  = (const float*)d_in[3];
    const float* b_ih0  = (const float*)d_in[4];
    const float* b_hh0  = (const float*)d_in[5];
    const float* W_ih1  = (const float*)d_in[6];
    const float* W_hh1  = (const float*)d_in[7];
    const float* b_ih1  = (const float*)d_in[8];
    const float* b_hh1  = (const float*)d_in[9];
    const float* fc_w   = (const float*)d_in[10];
    const float* fc_b   = (const float*)d_in[11];

    const int nblocks = (Bsz + GB - 1) / GB;   // 1366
    rnn2_fused<<<nblocks, NTHREADS, 0, stream>>>(
        x, hidden, W_ih0, W_hh0, b_ih0, b_hh0,
        W_ih1, W_hh1, b_ih1, b_hh1, fc_w, fc_b, (float*)d_out);
}